// Round 3
// baseline (82.712 us; speedup 1.0000x reference)
//
#include <hip/hip_runtime.h>
#include <math.h>

#define N_B 64
#define T_LEN 2048
#define D_DIM 512
#define NEG (-1e9f)

__device__ __forceinline__ float dot8(const float4& qa, const float4& qb,
                                      const float4& ka, const float4& kb) {
    return qa.x * ka.x + qa.y * ka.y + qa.z * ka.z + qa.w * ka.w
         + qb.x * kb.x + qb.y * kb.y + qb.z * kb.z + qb.w * kb.w;
}

// ---------------------------------------------------------------------------
// Kernel A: one block per (chunk c, batch n). Each of the 4 waves owns a
// contiguous RW-row slice and runs online softmax in registers, TWO rows per
// iteration: k-pair prefetched one iteration ahead, v-pair loaded in-iteration,
// two independent dot+butterfly chains interleaved, one rescale per pair.
// Lane owns d = 8*lane .. 8*lane+7. Waves merge once at the end via LDS.
// ---------------------------------------------------------------------------
__global__ __launch_bounds__(256) void attn_partial(
    const float* __restrict__ q,     // (N, D)
    const float* __restrict__ key,   // (T, N, D)
    const float* __restrict__ val,   // (T, N, D)
    const int*   __restrict__ lens,  // (N)
    float* __restrict__ m_ws,        // (N, C)
    float* __restrict__ l_ws,        // (N, C)
    float* __restrict__ o_ws,        // (N, C, D)
    int C)
{
    const int c    = blockIdx.x;
    const int n    = blockIdx.y;
    const int tid  = threadIdx.x;
    const int wave = tid >> 6;
    const int lane = tid & 63;
    const int TC   = T_LEN / C;   // rows per chunk
    const int RW   = TC >> 2;     // rows per wave (contiguous)
    const int t0   = c * TC;
    const int len_n = lens[n];
    const int d0   = 2 * tid;

    // Fully masked chunk with len>0: zero weight after combine. No reads.
    if (len_n > 0 && t0 >= len_n) {
        if (tid == 0) { m_ws[n * C + c] = -INFINITY; l_ws[n * C + c] = 0.0f; }
        *reinterpret_cast<float2*>(o_ws + ((size_t)n * C + c) * D_DIM + d0) =
            make_float2(0.0f, 0.0f);
        return;
    }

    __shared__ float acc_sm[4][D_DIM];   // per-wave partial contexts
    __shared__ float ml_sm[4][2];        // per-wave (m, l)

    const int    wstart  = t0 + wave * RW;
    const size_t rstride = (size_t)N_B * D_DIM;   // row stride in floats

    float acc[8];
    #pragma unroll
    for (int j = 0; j < 8; ++j) acc[j] = 0.0f;
    float m = -INFINITY, l = 0.0f;

    if (len_n == 0) {
        // Reference: all energies NEG -> uniform softmax -> mean of value.
        const float* vr = val + ((size_t)wstart * N_B + n) * D_DIM + 8 * lane;
        for (int i = 0; i < RW; ++i) {
            const float4 va = *reinterpret_cast<const float4*>(vr);
            const float4 vb = *reinterpret_cast<const float4*>(vr + 4);
            vr += rstride;
            acc[0] += va.x; acc[1] += va.y; acc[2] += va.z; acc[3] += va.w;
            acc[4] += vb.x; acc[5] += vb.y; acc[6] += vb.z; acc[7] += vb.w;
        }
        m = NEG;
        l = (float)RW;
    } else {
        int nact = len_n - wstart;          // active rows for this wave
        if (nact > RW) nact = RW;
        if (nact > 0) {
            const float4* q4 = reinterpret_cast<const float4*>(
                q + (size_t)n * D_DIM) + 2 * lane;
            const float4 qa = q4[0];
            const float4 qb = q4[1];

            const float* kr = key + ((size_t)wstart * N_B + n) * D_DIM + 8 * lane;
            const float* vr = val + ((size_t)wstart * N_B + n) * D_DIM + 8 * lane;

            // Preload first k-pair.
            float4 k0a = *reinterpret_cast<const float4*>(kr);
            float4 k0b = *reinterpret_cast<const float4*>(kr + 4);
            float4 k1a = k0a, k1b = k0b;
            if (nact > 1) {
                k1a = *reinterpret_cast<const float4*>(kr + rstride);
                k1b = *reinterpret_cast<const float4*>(kr + rstride + 4);
            }

            int i = 0;
            for (; i + 1 < nact; i += 2) {
                // Prefetch next k-pair (independent of this pair's chains).
                float4 n0a = k0a, n0b = k0b, n1a = k1a, n1b = k1b;
                if (i + 2 < nact) {
                    n0a = *reinterpret_cast<const float4*>(kr + 2 * rstride);
                    n0b = *reinterpret_cast<const float4*>(kr + 2 * rstride + 4);
                }
                if (i + 3 < nact) {
                    n1a = *reinterpret_cast<const float4*>(kr + 3 * rstride);
                    n1b = *reinterpret_cast<const float4*>(kr + 3 * rstride + 4);
                }
                kr += 2 * rstride;
                // This pair's value rows.
                const float4 v0a = *reinterpret_cast<const float4*>(vr);
                const float4 v0b = *reinterpret_cast<const float4*>(vr + 4);
                const float4 v1a = *reinterpret_cast<const float4*>(vr + rstride);
                const float4 v1b = *reinterpret_cast<const float4*>(vr + rstride + 4);
                vr += 2 * rstride;

                float e0 = dot8(qa, qb, k0a, k0b);
                float e1 = dot8(qa, qb, k1a, k1b);
                #pragma unroll
                for (int off = 32; off; off >>= 1) {
                    e0 += __shfl_xor(e0, off);
                    e1 += __shfl_xor(e1, off);
                }

                const float emax = fmaxf(e0, e1);
                if (emax > m) {                     // wave-uniform branch
                    const float sc = __expf(m - emax); // first iter: 0
                    l *= sc;
                    #pragma unroll
                    for (int j = 0; j < 8; ++j) acc[j] *= sc;
                    m = emax;
                }
                const float p0 = __expf(e0 - m);
                const float p1 = __expf(e1 - m);
                l += p0 + p1;
                acc[0] += p0 * v0a.x + p1 * v1a.x;
                acc[1] += p0 * v0a.y + p1 * v1a.y;
                acc[2] += p0 * v0a.z + p1 * v1a.z;
                acc[3] += p0 * v0a.w + p1 * v1a.w;
                acc[4] += p0 * v0b.x + p1 * v1b.x;
                acc[5] += p0 * v0b.y + p1 * v1b.y;
                acc[6] += p0 * v0b.z + p1 * v1b.z;
                acc[7] += p0 * v0b.w + p1 * v1b.w;

                k0a = n0a; k0b = n0b; k1a = n1a; k1b = n1b;
            }
            if (i < nact) {  // odd tail: single row, k already in k0
                const float4 v0a = *reinterpret_cast<const float4*>(vr);
                const float4 v0b = *reinterpret_cast<const float4*>(vr + 4);
                float e0 = dot8(qa, qb, k0a, k0b);
                #pragma unroll
                for (int off = 32; off; off >>= 1) e0 += __shfl_xor(e0, off);
                if (e0 > m) {
                    const float sc = __expf(m - e0);
                    l *= sc;
                    #pragma unroll
                    for (int j = 0; j < 8; ++j) acc[j] *= sc;
                    m = e0;
                }
                const float p0 = __expf(e0 - m);
                l += p0;
                acc[0] += p0 * v0a.x; acc[1] += p0 * v0a.y;
                acc[2] += p0 * v0a.z; acc[3] += p0 * v0a.w;
                acc[4] += p0 * v0b.x; acc[5] += p0 * v0b.y;
                acc[6] += p0 * v0b.z; acc[7] += p0 * v0b.w;
            }
        }
        // nact <= 0: (m,l,acc) stay (-inf, 0, 0) -> zeroed at merge.
    }

    // ---- merge the 4 waves' partials ----
    *reinterpret_cast<float4*>(&acc_sm[wave][8 * lane]) =
        make_float4(acc[0], acc[1], acc[2], acc[3]);
    *reinterpret_cast<float4*>(&acc_sm[wave][8 * lane + 4]) =
        make_float4(acc[4], acc[5], acc[6], acc[7]);
    if (lane == 0) { ml_sm[wave][0] = m; ml_sm[wave][1] = l; }
    __syncthreads();

    const float m0 = ml_sm[0][0], m1 = ml_sm[1][0];
    const float m2 = ml_sm[2][0], m3 = ml_sm[3][0];
    const float M  = fmaxf(fmaxf(m0, m1), fmaxf(m2, m3));  // finite here
    const float s0 = __expf(m0 - M), s1 = __expf(m1 - M);  // -inf waves -> 0
    const float s2 = __expf(m2 - M), s3 = __expf(m3 - M);

    float2 r;
    r.x = s0 * acc_sm[0][d0]     + s1 * acc_sm[1][d0]
        + s2 * acc_sm[2][d0]     + s3 * acc_sm[3][d0];
    r.y = s0 * acc_sm[0][d0 + 1] + s1 * acc_sm[1][d0 + 1]
        + s2 * acc_sm[2][d0 + 1] + s3 * acc_sm[3][d0 + 1];
    *reinterpret_cast<float2*>(o_ws + ((size_t)n * C + c) * D_DIM + d0) = r;

    if (tid == 0) {
        m_ws[n * C + c] = M;
        l_ws[n * C + c] = s0 * ml_sm[0][1] + s1 * ml_sm[1][1]
                        + s2 * ml_sm[2][1] + s3 * ml_sm[3][1];
    }
}

// ---------------------------------------------------------------------------
// Kernel B: combine C chunk-partials per batch with log-sum-exp merge.
// Grid (N, 2): block (n, h) handles d = h*256 + tid (scalar, coalesced).
// ---------------------------------------------------------------------------
__global__ __launch_bounds__(256) void attn_combine(
    const float* __restrict__ m_ws,  // (N, C)
    const float* __restrict__ l_ws,  // (N, C)
    const float* __restrict__ o_ws,  // (N, C, D)
    float* __restrict__ out,         // (N, D)
    int C)
{
    const int n   = blockIdx.x;
    const int d   = blockIdx.y * 256 + threadIdx.x;
    const int tid = threadIdx.x;

    __shared__ float s_sm[64];   // per-chunk scale exp(m_c - M), C <= 64
    __shared__ float S_sm;

    if (tid < 64) {
        const float m = (tid < C) ? m_ws[n * C + tid] : -INFINITY;
        float M = m;
        #pragma unroll
        for (int off = 32; off; off >>= 1) M = fmaxf(M, __shfl_xor(M, off));
        const float s = (tid < C) ? __expf(m - M) : 0.0f;  // -inf chunks -> 0
        s_sm[tid] = s;
        float S = s * ((tid < C) ? l_ws[n * C + tid] : 0.0f);
        #pragma unroll
        for (int off = 32; off; off >>= 1) S += __shfl_xor(S, off);
        if (tid == 0) S_sm = S;
    }
    __syncthreads();

    const float inv = 1.0f / S_sm;
    float acc = 0.0f;
    const float* op = o_ws + (size_t)n * C * D_DIM + d;
    for (int c = 0; c < C; ++c) {
        const float s = s_sm[c];
        if (s != 0.0f) acc += s * op[(size_t)c * D_DIM];
    }
    out[(size_t)n * D_DIM + d] = acc * inv;
}

extern "C" void kernel_launch(void* const* d_in, const int* in_sizes, int n_in,
                              void* d_out, int out_size, void* d_ws, size_t ws_size,
                              hipStream_t stream) {
    const float* q    = (const float*)d_in[0];
    const float* key  = (const float*)d_in[1];
    const float* val  = (const float*)d_in[2];
    const int*   lens = (const int*)d_in[3];
    float*       out  = (float*)d_out;

    // Workspace: m (N*C) + l (N*C) + o (N*C*D) floats. Shrink C if ws is tiny.
    int C = 64;
    while (C > 4 && (size_t)N_B * C * (D_DIM + 2) * sizeof(float) > ws_size) C >>= 1;

    float* m_ws = (float*)d_ws;
    float* l_ws = m_ws + (size_t)N_B * C;
    float* o_ws = l_ws + (size_t)N_B * C;

    attn_partial<<<dim3(C, N_B), 256, 0, stream>>>(q, key, val, lens,
                                                   m_ws, l_ws, o_ws, C);
    attn_combine<<<dim3(N_B, D_DIM / 256), 256, 0, stream>>>(m_ws, l_ws, o_ws,
                                                             out, C);
}

// Round 4
// 67.289 us; speedup vs baseline: 1.2292x; 1.2292x over previous
//
#include <hip/hip_runtime.h>
#include <math.h>

#define N_B 64
#define T_LEN 2048
#define D_DIM 512
#define NEG (-1e9f)

__device__ __forceinline__ float dot8(const float4& qa, const float4& qb,
                                      const float4& ka, const float4& kb) {
    return qa.x * ka.x + qa.y * ka.y + qa.z * ka.z + qa.w * ka.w
         + qb.x * kb.x + qb.y * kb.y + qb.z * kb.z + qb.w * kb.w;
}

// ---------------------------------------------------------------------------
// Kernel A: one block per (chunk c, batch n). Each of the 4 waves owns a
// contiguous RW-row slice and runs online softmax in registers, one row per
// iteration: v row + next k row issued up front, dot(q,k) + 64-lane butterfly,
// online (m,l) update, acc += p*v. Lane owns d = 8*lane .. 8*lane+7.
// Waves merge once at the end via LDS. C=32 -> RW=16 rows/wave.
// Fully-masked chunks (len>0) skip all key/value reads.
// ---------------------------------------------------------------------------
__global__ __launch_bounds__(256) void attn_partial(
    const float* __restrict__ q,     // (N, D)
    const float* __restrict__ key,   // (T, N, D)
    const float* __restrict__ val,   // (T, N, D)
    const int*   __restrict__ lens,  // (N)
    float* __restrict__ m_ws,        // (N, C)
    float* __restrict__ l_ws,        // (N, C)
    float* __restrict__ o_ws,        // (N, C, D)
    int C)
{
    const int c    = blockIdx.x;
    const int n    = blockIdx.y;
    const int tid  = threadIdx.x;
    const int wave = tid >> 6;
    const int lane = tid & 63;
    const int TC   = T_LEN / C;   // rows per chunk
    const int RW   = TC >> 2;     // rows per wave (contiguous)
    const int t0   = c * TC;
    const int len_n = lens[n];
    const int d0   = 2 * tid;

    // Fully masked chunk with len>0: zero weight after combine. No reads.
    if (len_n > 0 && t0 >= len_n) {
        if (tid == 0) { m_ws[n * C + c] = -INFINITY; l_ws[n * C + c] = 0.0f; }
        *reinterpret_cast<float2*>(o_ws + ((size_t)n * C + c) * D_DIM + d0) =
            make_float2(0.0f, 0.0f);
        return;
    }

    __shared__ float acc_sm[4][D_DIM];   // per-wave partial contexts
    __shared__ float ml_sm[4][2];        // per-wave (m, l)

    const int    wstart  = t0 + wave * RW;
    const size_t rstride = (size_t)N_B * D_DIM;   // row stride in floats

    float acc[8];
    #pragma unroll
    for (int j = 0; j < 8; ++j) acc[j] = 0.0f;
    float m = -INFINITY, l = 0.0f;

    if (len_n == 0) {
        // Reference: all energies NEG -> uniform softmax -> mean of value.
        const float* vr = val + ((size_t)wstart * N_B + n) * D_DIM + 8 * lane;
        for (int i = 0; i < RW; ++i) {
            const float4 va = *reinterpret_cast<const float4*>(vr);
            const float4 vb = *reinterpret_cast<const float4*>(vr + 4);
            vr += rstride;
            acc[0] += va.x; acc[1] += va.y; acc[2] += va.z; acc[3] += va.w;
            acc[4] += vb.x; acc[5] += vb.y; acc[6] += vb.z; acc[7] += vb.w;
        }
        m = NEG;
        l = (float)RW;
    } else {
        int nact = len_n - wstart;          // active rows for this wave
        if (nact > RW) nact = RW;
        if (nact > 0) {
            const float4* q4 = reinterpret_cast<const float4*>(
                q + (size_t)n * D_DIM) + 2 * lane;
            const float4 qa = q4[0];
            const float4 qb = q4[1];

            const float* kr = key + ((size_t)wstart * N_B + n) * D_DIM + 8 * lane;
            const float* vr = val + ((size_t)wstart * N_B + n) * D_DIM + 8 * lane;

            float4 ka = *reinterpret_cast<const float4*>(kr);
            float4 kb = *reinterpret_cast<const float4*>(kr + 4);
            float4 na = ka, nb = kb;

            for (int i = 0; i < nact; ++i) {
                // Issue this row's value load first (independent stream).
                const float4 va = *reinterpret_cast<const float4*>(vr);
                const float4 vb = *reinterpret_cast<const float4*>(vr + 4);
                vr += rstride;
                // Prefetch next key row (independent of this row's chain).
                if (i + 1 < nact) {
                    na = *reinterpret_cast<const float4*>(kr + rstride);
                    nb = *reinterpret_cast<const float4*>(kr + rstride + 4);
                }
                kr += rstride;

                float e = dot8(qa, qb, ka, kb);
                #pragma unroll
                for (int off = 32; off; off >>= 1) e += __shfl_xor(e, off);

                if (e > m) {                       // wave-uniform branch
                    const float sc = __expf(m - e); // first iter: exp(-inf)=0
                    l *= sc;
                    #pragma unroll
                    for (int j = 0; j < 8; ++j) acc[j] *= sc;
                    m = e;
                }
                const float p = __expf(e - m);
                l += p;
                acc[0] += p * va.x; acc[1] += p * va.y;
                acc[2] += p * va.z; acc[3] += p * va.w;
                acc[4] += p * vb.x; acc[5] += p * vb.y;
                acc[6] += p * vb.z; acc[7] += p * vb.w;

                ka = na; kb = nb;
            }
        }
        // nact <= 0: (m,l,acc) stay (-inf, 0, 0) -> zeroed at merge.
    }

    // ---- merge the 4 waves' partials ----
    *reinterpret_cast<float4*>(&acc_sm[wave][8 * lane]) =
        make_float4(acc[0], acc[1], acc[2], acc[3]);
    *reinterpret_cast<float4*>(&acc_sm[wave][8 * lane + 4]) =
        make_float4(acc[4], acc[5], acc[6], acc[7]);
    if (lane == 0) { ml_sm[wave][0] = m; ml_sm[wave][1] = l; }
    __syncthreads();

    const float m0 = ml_sm[0][0], m1 = ml_sm[1][0];
    const float m2 = ml_sm[2][0], m3 = ml_sm[3][0];
    const float M  = fmaxf(fmaxf(m0, m1), fmaxf(m2, m3));  // finite here
    const float s0 = __expf(m0 - M), s1 = __expf(m1 - M);  // -inf waves -> 0
    const float s2 = __expf(m2 - M), s3 = __expf(m3 - M);

    float2 r;
    r.x = s0 * acc_sm[0][d0]     + s1 * acc_sm[1][d0]
        + s2 * acc_sm[2][d0]     + s3 * acc_sm[3][d0];
    r.y = s0 * acc_sm[0][d0 + 1] + s1 * acc_sm[1][d0 + 1]
        + s2 * acc_sm[2][d0 + 1] + s3 * acc_sm[3][d0 + 1];
    *reinterpret_cast<float2*>(o_ws + ((size_t)n * C + c) * D_DIM + d0) = r;

    if (tid == 0) {
        m_ws[n * C + c] = M;
        l_ws[n * C + c] = s0 * ml_sm[0][1] + s1 * ml_sm[1][1]
                        + s2 * ml_sm[2][1] + s3 * ml_sm[3][1];
    }
}

// ---------------------------------------------------------------------------
// Kernel B: combine C chunk-partials per batch with log-sum-exp merge.
// Grid (N, 2): block (n, h) handles d = h*256 + tid (scalar, coalesced).
// ---------------------------------------------------------------------------
__global__ __launch_bounds__(256) void attn_combine(
    const float* __restrict__ m_ws,  // (N, C)
    const float* __restrict__ l_ws,  // (N, C)
    const float* __restrict__ o_ws,  // (N, C, D)
    float* __restrict__ out,         // (N, D)
    int C)
{
    const int n   = blockIdx.x;
    const int d   = blockIdx.y * 256 + threadIdx.x;
    const int tid = threadIdx.x;

    __shared__ float s_sm[64];   // per-chunk scale exp(m_c - M), C <= 64
    __shared__ float S_sm;

    if (tid < 64) {
        const float m = (tid < C) ? m_ws[n * C + tid] : -INFINITY;
        float M = m;
        #pragma unroll
        for (int off = 32; off; off >>= 1) M = fmaxf(M, __shfl_xor(M, off));
        const float s = (tid < C) ? __expf(m - M) : 0.0f;  // -inf chunks -> 0
        s_sm[tid] = s;
        float S = s * ((tid < C) ? l_ws[n * C + tid] : 0.0f);
        #pragma unroll
        for (int off = 32; off; off >>= 1) S += __shfl_xor(S, off);
        if (tid == 0) S_sm = S;
    }
    __syncthreads();

    const float inv = 1.0f / S_sm;
    float acc = 0.0f;
    const float* op = o_ws + (size_t)n * C * D_DIM + d;
    for (int c = 0; c < C; ++c) {
        const float s = s_sm[c];
        if (s != 0.0f) acc += s * op[(size_t)c * D_DIM];
    }
    out[(size_t)n * D_DIM + d] = acc * inv;
}

extern "C" void kernel_launch(void* const* d_in, const int* in_sizes, int n_in,
                              void* d_out, int out_size, void* d_ws, size_t ws_size,
                              hipStream_t stream) {
    const float* q    = (const float*)d_in[0];
    const float* key  = (const float*)d_in[1];
    const float* val  = (const float*)d_in[2];
    const int*   lens = (const int*)d_in[3];
    float*       out  = (float*)d_out;

    // Workspace: m (N*C) + l (N*C) + o (N*C*D) floats. Shrink C if ws is tiny.
    int C = 32;
    while (C > 4 && (size_t)N_B * C * (D_DIM + 2) * sizeof(float) > ws_size) C >>= 1;

    float* m_ws = (float*)d_ws;
    float* l_ws = m_ws + (size_t)N_B * C;
    float* o_ws = l_ws + (size_t)N_B * C;

    attn_partial<<<dim3(C, N_B), 256, 0, stream>>>(q, key, val, lens,
                                                   m_ws, l_ws, o_ws, C);
    attn_combine<<<dim3(N_B, D_DIM / 256), 256, 0, stream>>>(m_ws, l_ws, o_ws,
                                                             out, C);
}